// Round 7
// baseline (211.853 us; speedup 1.0000x reference)
//
#include <hip/hip_runtime.h>
#include <cstdint>
#include <cstddef>

#define N_TOKENS 65536
#define DIM 64
#define K_CODES 1024
#define NTH 256
#define NTHM 512                // vq_main threads (8 waves)
#define TPB 128                 // tokens per main block (grid 512)
#define NCH 16                  // chunks of 64 codes
#define NBLK (N_TOKENS / TPB)   // 512 main blocks

// out layout (floats): [0]=loss, [1..4194304]=quantized, [4194305]=perplexity,
// [4194306..4259841]=indices
#define OFF_Q 1
#define OFF_PERP 4194305
#define OFF_IDX 4194306

// approx-vs-exact margin. m = x.w - 0.5*s2 (max semantics), d = -2*m exactly, so
// (d2-d1) < MARGIN <=> (m1-m2) < MARGIN/2. Tokens failing the margin are rescanned
// bit-exactly in this block's tail phase (same arithmetic as the validated
// fallback kernel of rounds 0-3).
#define MARGIN 1.5e-4f
#define HMARGIN 7.5e-5f

// ws byte offsets
#define WS_LOSS   0        // double
#define WS_TICKET 8        // int (block-completion ticket)
#define WS_COUNTS 16       // int[1024]
#define WS_WHI    4112     // ushort[65536], 16B aligned, MFMA-swizzled
#define WS_WLO    135184   // ushort[65536]
#define WS_S2     266256   // float[1024]

typedef __attribute__((ext_vector_type(8))) short  s16x8;
typedef __attribute__((ext_vector_type(4))) float  f32x4;

__device__ __forceinline__ float fmulr(float a, float b){ return __fmul_rn(a,b); }
__device__ __forceinline__ float faddr(float a, float b){ return __fadd_rn(a,b); }

__device__ __forceinline__ unsigned short f2bf(float f) {
    unsigned u = __float_as_uint(f);
    unsigned r = u + 0x7fffu + ((u >> 16) & 1u);   // RNE
    return (unsigned short)(r >> 16);
}
__device__ __forceinline__ float bf2f(unsigned short h) {
    return __uint_as_float(((unsigned)h) << 16);
}

// numpy (AVX512 pairwise) sum of 64 squares — validated bit-exact in rounds 1-2
__device__ float sumsq64_np(const float* __restrict__ p) {
    float s[16];
    #pragma unroll
    for (int l = 0; l < 16; ++l) {
        float a0 = fmulr(p[l],      p[l]);
        float a1 = fmulr(p[l + 16], p[l + 16]);
        float a2 = fmulr(p[l + 32], p[l + 32]);
        float a3 = fmulr(p[l + 48], p[l + 48]);
        s[l] = faddr(faddr(a0, a1), faddr(a2, a3));
    }
    #pragma unroll
    for (int len = 8; len >= 1; len >>= 1)
        #pragma unroll
        for (int l = 0; l < len; ++l)
            s[l] = faddr(s[l], s[l + len]);
    return s[0];
}

__device__ __forceinline__ void async_copy16(const void* g, void* l) {
    __builtin_amdgcn_global_load_lds(
        (const __attribute__((address_space(1))) void*)g,
        (__attribute__((address_space(3))) void*)l, 16, 0, 0);
}

// ---------------- prep: W -> swizzled bf16 hi/lo, exact s2, zero accumulators ----
__global__ void vq_prep(const float* __restrict__ W, unsigned short* __restrict__ Whi,
                        unsigned short* __restrict__ Wlo, float* __restrict__ s2g,
                        int* __restrict__ counts, int* __restrict__ ticket,
                        double* __restrict__ loss_acc) {
    int gid = blockIdx.x * NTH + threadIdx.x;   // 64 blocks -> 16384 threads
    for (int e = gid; e < K_CODES * DIM; e += 16384) {
        float x = W[e];
        unsigned short hi = f2bf(x);
        unsigned short lo = f2bf(__fsub_rn(x, bf2f(hi)));
        int j = e >> 6, k = e & 63;
        int pos = j * 64 + (((k >> 3) ^ (j & 7)) << 3) + (k & 7);
        Whi[pos] = hi; Wlo[pos] = lo;
    }
    if (gid < K_CODES) { s2g[gid] = sumsq64_np(W + gid * 64); counts[gid] = 0; }
    if (gid == 0) { *loss_acc = 0.0; *ticket = 0; }
}

// ---------------- final scalars (run by the last main block via ticket) ----------
__device__ void final_scalars(int* __restrict__ counts, double* __restrict__ loss_acc,
                              float* __restrict__ out, int tid, double* hred) {
    double h = 0.0;
    for (int j = tid; j < K_CODES; j += NTHM) {
        int cj = atomicAdd(&counts[j], 0);            // coherent read
        double p = (double)cj / 65536.0;
        h += p * log(p + 1e-10);
    }
    #pragma unroll
    for (int off = 32; off >= 1; off >>= 1) h += __shfl_down(h, off, 64);
    if ((tid & 63) == 0) hred[tid >> 6] = h;
    __syncthreads();
    if (tid == 0) {
        double H = 0.0;
        #pragma unroll
        for (int w = 0; w < 8; ++w) H += hred[w];
        out[OFF_PERP] = (float)exp(-H);
        double ls = atomicAdd(loss_acc, 0.0);         // coherent read
        float Lf = (float)(ls / 4194304.0);
        out[0] = faddr(Lf, fmulr(0.25f, Lf));
    }
}

// ---------------- main: MFMA approx top2 + in-block exact fallback + scalars -----
// Hot loop byte-equivalent to round-1's proven 56us kernel: 8 waves (tg 0..3
// token groups x chd 0..1 code halves), plain __syncthreads dbuf pipeline.
// New: (a) per-block exact-rescan tail for this block's own margin-failing
// tokens (dead X-staging LDS reused for fp32 W chunks); (b) single global
// ticket -> last block computes perplexity/loss (kills 2 kernels + gaps).
// launch_bounds min-waves=2 (cap 256 regs): 4 forced cap 128 -> R5 spilled;
// LDS ~73.7KB -> 2 blocks/CU is the occupancy limiter regardless of regs.
__global__ __launch_bounds__(NTHM, 2)
void vq_main(const float* __restrict__ X, const float* __restrict__ W,
             const unsigned short* __restrict__ WhiG, const unsigned short* __restrict__ WloG,
             const float* __restrict__ s2g, float* __restrict__ out,
             double* __restrict__ loss_acc, int* __restrict__ counts,
             int* __restrict__ ticket) {
    __shared__ __align__(16) char uA[32768];   // xs_hi|xs_lo  -> tail: fp32 W chunk
    __shared__ __align__(16) char uB[32768];   // ws bf16 dbuf -> tail: fp32 X rows
    __shared__ __align__(16) float s2s[K_CODES];
    __shared__ float sm1[2][TPB];              // merge; sm1 -> tail: tbest (u64[128])
    __shared__ float sm2[2][TPB];              //        sm2 -> tail: s1f
    __shared__ int   si1[2][TPB];
    __shared__ int fidx[TPB];
    __shared__ int flist[TPB];
    __shared__ int fcount, lastflag;
    __shared__ double lred[8];

    unsigned short* xs_hi = (unsigned short*)uA;
    unsigned short* xs_lo = (unsigned short*)(uA + 16384);

    const int tid  = threadIdx.x;
    const int lane = tid & 63, wave = tid >> 6;
    const int quad = lane >> 4, lrow = lane & 15;
    const int tg   = wave & 3;        // token group: 32 tokens
    const int chd  = wave >> 2;       // code half: 32 of each 64-code chunk
    const int t0   = blockIdx.x * TPB;

    if (tid == 0) fcount = 0;

    // prefetch chunk 0 first so it overlaps X staging
    {
        const char* gh = (const char*)WhiG;
        const char* gl = (const char*)WloG;
        char* lh = uB + wave * 1024;               // buf0 hi
        char* ll = uB + 16384 + wave * 1024;       // buf0 lo
        async_copy16(gh + tid * 16, lh);
        async_copy16(gl + tid * 16, ll);
    }
    // stage s2 (4KB)
    if (tid < 256) *(f32x4*)&s2s[tid * 4] = *(const f32x4*)&s2g[tid * 4];
    // stage X tile as swizzled bf16 hi/lo (1024 groups of 8 floats)
    #pragma unroll
    for (int i = 0; i < 2; ++i) {
        int g = tid + NTHM * i;
        int t = g >> 3, kb = g & 7;
        const float* src = X + (size_t)(t0 + t) * DIM + kb * 8;
        float v[8];
        *(f32x4*)v       = *(const f32x4*)src;
        *(f32x4*)(v + 4) = *(const f32x4*)(src + 4);
        unsigned short h[8], l[8];
        #pragma unroll
        for (int k = 0; k < 8; ++k) {
            h[k] = f2bf(v[k]);
            l[k] = f2bf(__fsub_rn(v[k], bf2f(h[k])));
        }
        int base = t * 64 + ((kb ^ (t & 7)) << 3);
        *(s16x8*)&xs_hi[base] = *(s16x8*)h;
        *(s16x8*)&xs_lo[base] = *(s16x8*)l;
    }
    __syncthreads();   // X/s2 staged, chunk-0 prefetch drained

    // A fragments in registers for the whole kernel: wave owns 32 tokens
    s16x8 a_h0[2], a_h1[2], a_l0[2], a_l1[2];
    #pragma unroll
    for (int rt = 0; rt < 2; ++rt) {
        int tf = tg * 32 + rt * 16 + lrow;
        int sA = tf & 7;
        a_h0[rt] = *(const s16x8*)&xs_hi[tf * 64 + (((0 + quad) ^ sA) << 3)];
        a_h1[rt] = *(const s16x8*)&xs_hi[tf * 64 + (((4 + quad) ^ sA) << 3)];
        a_l0[rt] = *(const s16x8*)&xs_lo[tf * 64 + (((0 + quad) ^ sA) << 3)];
        a_l1[rt] = *(const s16x8*)&xs_lo[tf * 64 + (((4 + quad) ^ sA) << 3)];
    }

    // top-2 of acc (max semantics; d = -2*acc exactly)
    float m1v[8], m2v[8]; int m1i[8];
    #pragma unroll
    for (int ri = 0; ri < 8; ++ri) { m1v[ri] = -3.4e38f; m2v[ri] = -3.4e38f; m1i[ri] = 0x7fffffff; }

    for (int ch = 0; ch < NCH; ++ch) {
        const int buf = ch & 1;
        if (ch < NCH - 1) {   // prefetch next chunk into other buffer
            const char* gh = (const char*)WhiG + (ch + 1) * 8192;
            const char* gl = (const char*)WloG + (ch + 1) * 8192;
            char* lh = uB + (buf ^ 1) * 8192 + wave * 1024;
            char* ll = uB + 16384 + (buf ^ 1) * 8192 + wave * 1024;
            async_copy16(gh + tid * 16, lh);
            async_copy16(gl + tid * 16, ll);
        }
        const unsigned short* wh = (const unsigned short*)(uB + buf * 8192);
        const unsigned short* wl = (const unsigned short*)(uB + 16384 + buf * 8192);
        #pragma unroll
        for (int ct2 = 0; ct2 < 2; ++ct2) {
            int lc = chd * 32 + ct2 * 16 + lrow;  // local code (lane's C-column)
            int sB = lrow & 7;
            const unsigned short* bh = &wh[lc * 64];
            const unsigned short* bl = &wl[lc * 64];
            s16x8 b_h0 = *(const s16x8*)&bh[((0 + quad) ^ sB) << 3];
            s16x8 b_h1 = *(const s16x8*)&bh[((4 + quad) ^ sB) << 3];
            s16x8 b_l0 = *(const s16x8*)&bl[((0 + quad) ^ sB) << 3];
            s16x8 b_l1 = *(const s16x8*)&bl[((4 + quad) ^ sB) << 3];
            int jcode = ch * 64 + lc;
            float s2v = s2s[jcode];
            float ainit = fmulr(-0.5f, s2v);
            #pragma unroll
            for (int rt = 0; rt < 2; ++rt) {
                f32x4 acc = {ainit, ainit, ainit, ainit};   // acc = x.w - 0.5*s2
                acc = __builtin_amdgcn_mfma_f32_16x16x32_bf16(a_h0[rt], b_h0, acc, 0, 0, 0);
                acc = __builtin_amdgcn_mfma_f32_16x16x32_bf16(a_h1[rt], b_h1, acc, 0, 0, 0);
                acc = __builtin_amdgcn_mfma_f32_16x16x32_bf16(a_h0[rt], b_l0, acc, 0, 0, 0);
                acc = __builtin_amdgcn_mfma_f32_16x16x32_bf16(a_h1[rt], b_l1, acc, 0, 0, 0);
                acc = __builtin_amdgcn_mfma_f32_16x16x32_bf16(a_l0[rt], b_h0, acc, 0, 0, 0);
                acc = __builtin_amdgcn_mfma_f32_16x16x32_bf16(a_l1[rt], b_h1, acc, 0, 0, 0);
                #pragma unroll
                for (int r = 0; r < 4; ++r) {
                    float a = acc[r];
                    int ri = rt * 4 + r;
                    bool gt = a > m1v[ri];      // strict: keeps earliest code on ties
                    float sec = gt ? m1v[ri] : a;
                    m2v[ri] = fmaxf(m2v[ri], sec);
                    m1v[ri] = gt ? a : m1v[ri];
                    m1i[ri] = gt ? jcode : m1i[ri];
                }
            }
        }
        __syncthreads();   // drains next-chunk prefetch; protects buf reuse
    }

    // butterfly top-2 merge across the 16 lrow lanes (codes disjoint per lane)
    #pragma unroll
    for (int m = 1; m <= 8; m <<= 1) {
        #pragma unroll
        for (int ri = 0; ri < 8; ++ri) {
            float o1v = __shfl_xor(m1v[ri], m, 64);
            int   o1i = __shfl_xor(m1i[ri], m, 64);
            float o2v = __shfl_xor(m2v[ri], m, 64);
            bool take = (o1v > m1v[ri]) || (o1v == m1v[ri] && o1i < m1i[ri]);
            float loser = take ? m1v[ri] : o1v;
            m2v[ri] = fmaxf(fmaxf(m2v[ri], o2v), loser);
            if (take) { m1v[ri] = o1v; m1i[ri] = o1i; }
        }
    }
    // per-half results -> LDS for cross-wave merge (wave pairs share tokens)
    if (lrow == 0) {
        #pragma unroll
        for (int ri = 0; ri < 8; ++ri) {
            int rt = ri >> 2, r = ri & 3;
            int t = tg * 32 + rt * 16 + quad * 4 + r;
            sm1[chd][t] = m1v[ri];
            sm2[chd][t] = m2v[ri];
            si1[chd][t] = m1i[ri];
        }
    }
    __syncthreads();
    if (tid < TPB) {
        int t = tid;
        float a1 = sm1[0][t], b1 = sm1[1][t];
        int   ia = si1[0][t], ib = si1[1][t];
        float a2 = sm2[0][t], b2 = sm2[1][t];
        bool take = (b1 > a1) || (b1 == a1 && ib < ia);
        float w1 = take ? b1 : a1;
        int   wi = take ? ib : ia;
        float loser = take ? a1 : b1;
        float w2 = fmaxf(fmaxf(a2, b2), loser);
        bool fb = __fsub_rn(w1, w2) < HMARGIN;   // == (d2 - d1) < MARGIN
        fidx[t] = fb ? (wi | (int)0x80000000) : wi;
        if (fb) { int p = atomicAdd(&fcount, 1); flist[p] = t; }
    }
    __syncthreads();

    // epilogue for certain tokens, float4-vectorized (lsum stays in regs)
    double lsum = 0.0;
    #pragma unroll
    for (int i = 0; i < 4; ++i) {
        int e4 = tid + NTHM * i;             // 0..2047 float4 groups
        int t = e4 >> 4, d4 = (e4 & 15) * 4;
        int iv = fidx[t];
        if (iv >= 0) {
            f32x4 q = *(const f32x4*)&W[iv * 64 + d4];
            f32x4 x = *(const f32x4*)&X[(size_t)(t0 + t) * 64 + d4];
            *(f32x4*)&out[(size_t)OFF_Q + (size_t)(t0 + t) * 64 + d4] = q;
            #pragma unroll
            for (int c = 0; c < 4; ++c) {
                float df = __fsub_rn(q[c], x[c]);
                lsum += (double)fmulr(df, df);
            }
        }
    }
    if (tid < TPB) {
        int iv = fidx[tid];
        if (iv >= 0) {
            atomicAdd(&counts[iv], 1);
            out[(size_t)OFF_IDX + t0 + tid] = (float)iv;
        }
    }

    // -------- tail: bit-exact rescan of this block's margin-failing tokens ------
    // Same arithmetic/order as the rounds-0-3 fallback kernel (validated):
    // s1 = sumsq64_np(global X row); acc = sequential fmaf chain over 16 f32x4;
    // d = (s1 + s2) + (-2*acc); argmin via packed u64 (d>0: s1 dominates).
    const int fc = fcount;
    if (fc > 0) {
        float* xsr = (float*)uB;                           // [128][64] fp32 rows
        float* wck = (float*)uA;                           // [64][64] fp32, swizzled
        unsigned long long* tbest = (unsigned long long*)sm1;   // [128]
        float* s1f = (float*)sm2;                          // [128]
        for (int g = tid; g < fc * 16; g += NTHM) {
            int ti = g >> 4, kb = g & 15;
            int tok = t0 + flist[ti];
            *(f32x4*)&xsr[ti * 64 + kb * 4] =
                *(const f32x4*)&X[(size_t)tok * 64 + kb * 4];
        }
        if (tid < fc) {
            tbest[tid] = ~0ULL;
            s1f[tid] = sumsq64_np(X + (size_t)(t0 + flist[tid]) * 64);
        }
        __syncthreads();
        for (int ch = 0; ch < NCH; ++ch) {
            #pragma unroll
            for (int i = 0; i < 2; ++i) {      // stage 64x64 fp32 W chunk, swizzled
                int g = tid + NTHM * i;        // 0..1023 float4 groups
                int jl = g >> 4, kb = g & 15;
                f32x4 v = *(const f32x4*)&W[(size_t)(ch * 64 + jl) * 64 + kb * 4];
                *(f32x4*)&wck[jl * 64 + ((kb ^ ((jl >> 3) & 7)) << 2)] = v;
            }
            __syncthreads();
            for (int p = tid; p < fc * 64; p += NTHM) {
                int ti = p >> 6, c = p & 63;   // per wave: one token, lanes=codes
                float acc = 0.0f;
                #pragma unroll
                for (int kb = 0; kb < 16; ++kb) {
                    f32x4 xv = *(const f32x4*)&xsr[ti * 64 + kb * 4];
                    f32x4 wv = *(const f32x4*)&wck[c * 64 + ((kb ^ ((c >> 3) & 7)) << 2)];
                    acc = __builtin_fmaf(xv[0], wv[0], acc);
                    acc = __builtin_fmaf(xv[1], wv[1], acc);
                    acc = __builtin_fmaf(xv[2], wv[2], acc);
                    acc = __builtin_fmaf(xv[3], wv[3], acc);
                }
                int j = ch * 64 + c;
                float d = faddr(faddr(s1f[ti], s2s[j]), fmulr(-2.0f, acc));
                unsigned long long pk =
                    ((unsigned long long)__float_as_uint(d) << 32) |
                    (unsigned long long)(unsigned int)j;
                // in-wave u64 min (lanes hold disjoint codes of the same token)
                #pragma unroll
                for (int m = 32; m >= 1; m >>= 1) {
                    unsigned long long o =
                        ((unsigned long long)(unsigned)__shfl_xor((int)(pk >> 32), m, 64) << 32) |
                        (unsigned long long)(unsigned)__shfl_xor((int)(pk & 0xffffffffu), m, 64);
                    pk = (o < pk) ? o : pk;
                }
                if (lane == 0) atomicMin(&tbest[ti], pk);
            }
            __syncthreads();
        }
        if (tid < fc) {
            int idx = (int)(tbest[tid] & 0xffffffffu);
            int t = flist[tid];
            fidx[t] = idx;                                  // resolved
            out[(size_t)OFF_IDX + t0 + t] = (float)idx;
            atomicAdd(&counts[idx], 1);
        }
        __syncthreads();
        for (int g = tid; g < fc * 16; g += NTHM) {
            int ti = g >> 4, d4 = (g & 15) * 4;
            int t = flist[ti];
            int idx = fidx[t];
            f32x4 q = *(const f32x4*)&W[idx * 64 + d4];
            f32x4 x = *(const f32x4*)&xsr[ti * 64 + d4];    // bit-equal copy of X row
            *(f32x4*)&out[(size_t)OFF_Q + (size_t)(t0 + t) * 64 + d4] = q;
            #pragma unroll
            for (int c = 0; c < 4; ++c) {
                float df = __fsub_rn(q[c], x[c]);
                lsum += (double)fmulr(df, df);
            }
        }
    }

    // -------- loss reduction + global ticket -> last block emits scalars --------
    #pragma unroll
    for (int off = 32; off >= 1; off >>= 1) lsum += __shfl_down(lsum, off, 64);
    if (lane == 0) lred[wave] = lsum;
    __syncthreads();
    if (tid == 0) {
        double s = 0.0;
        #pragma unroll
        for (int w = 0; w < 8; ++w) s += lred[w];
        atomicAdd(loss_acc, s);
    }
    __threadfence();
    __syncthreads();
    if (tid == 0) lastflag = (atomicAdd(ticket, 1) == NBLK - 1);
    __syncthreads();
    if (lastflag) {
        __threadfence();
        final_scalars(counts, loss_acc, out, tid, lred);
    }
}

extern "C" void kernel_launch(void* const* d_in, const int* in_sizes, int n_in,
                              void* d_out, int out_size, void* d_ws, size_t ws_size,
                              hipStream_t stream) {
    const float* X = (const float*)d_in[0];
    const float* W = (const float*)d_in[1];
    float* out = (float*)d_out;
    char* ws = (char*)d_ws;
    double* loss_acc = (double*)(ws + WS_LOSS);
    int* ticket = (int*)(ws + WS_TICKET);
    int* counts = (int*)(ws + WS_COUNTS);
    unsigned short* Whi = (unsigned short*)(ws + WS_WHI);
    unsigned short* Wlo = (unsigned short*)(ws + WS_WLO);
    float* s2g = (float*)(ws + WS_S2);

    vq_prep<<<64, NTH, 0, stream>>>(W, Whi, Wlo, s2g, counts, ticket, loss_acc);
    vq_main<<<NBLK, NTHM, 0, stream>>>(X, W, Whi, Wlo, s2g, out,
                                       loss_acc, counts, ticket);
}

// Round 8
// 195.510 us; speedup vs baseline: 1.0836x; 1.0836x over previous
//
#include <hip/hip_runtime.h>
#include <cstdint>
#include <cstddef>

#define N_TOKENS 65536
#define DIM 64
#define K_CODES 1024
#define NTH 256
#define NTHM 512                // vq_main threads (8 waves)
#define TPB 128                 // tokens per main block (grid 512)
#define NCH 16                  // chunks of 64 codes
#define NBLK (N_TOKENS / TPB)   // 512 main blocks

// out layout (floats): [0]=loss, [1..4194304]=quantized, [4194305]=perplexity,
// [4194306..4259841]=indices
#define OFF_Q 1
#define OFF_PERP 4194305
#define OFF_IDX 4194306

// approx-vs-exact margin. m = x.w - 0.5*s2 (max semantics), d = -2*m exactly.
// |approx_m - exact_m| <= E ~ 2.3e-5; HMARGIN = 7.5e-5 > 2E strictly.
//  - w1 - w2 >= HMARGIN -> i1 is the exact argmin (rounds 0-3 proven).
//  - else: exact winner j* satisfies m_j* > w1 - HMARGIN (any other code's exact
//    m is strictly lower than i1's). The hot loop records a per-lane candidate
//    bitmask: bit set iff a + HM > running_max_before_update. Running max only
//    grows and is <= w1, so the mask is a SUPERSET of {j : m_j > w1 - HM}.
//    Resolve = bit-exact dots (validated fmaf chain) over mask codes only
//    (~1 per lane), packed-u64 argmin == the old full-rescan fallback result.
#define MARGIN 1.5e-4f
#define HMARGIN 7.5e-5f

// ws byte offsets
#define WS_LOSS   0        // double
#define WS_TICKET 8        // int (block-completion ticket)
#define WS_COUNTS 16       // int[1024]
#define WS_WHI    4112     // ushort[65536], 16B aligned, MFMA-swizzled
#define WS_WLO    135184   // ushort[65536]
#define WS_S2     266256   // float[1024]

typedef __attribute__((ext_vector_type(8))) short  s16x8;
typedef __attribute__((ext_vector_type(4))) float  f32x4;

__device__ __forceinline__ float fmulr(float a, float b){ return __fmul_rn(a,b); }
__device__ __forceinline__ float faddr(float a, float b){ return __fadd_rn(a,b); }

__device__ __forceinline__ unsigned short f2bf(float f) {
    unsigned u = __float_as_uint(f);
    unsigned r = u + 0x7fffu + ((u >> 16) & 1u);   // RNE
    return (unsigned short)(r >> 16);
}
__device__ __forceinline__ float bf2f(unsigned short h) {
    return __uint_as_float(((unsigned)h) << 16);
}

// numpy (AVX512 pairwise) sum of 64 squares — validated bit-exact in rounds 1-2
__device__ float sumsq64_np(const float* __restrict__ p) {
    float s[16];
    #pragma unroll
    for (int l = 0; l < 16; ++l) {
        float a0 = fmulr(p[l],      p[l]);
        float a1 = fmulr(p[l + 16], p[l + 16]);
        float a2 = fmulr(p[l + 32], p[l + 32]);
        float a3 = fmulr(p[l + 48], p[l + 48]);
        s[l] = faddr(faddr(a0, a1), faddr(a2, a3));
    }
    #pragma unroll
    for (int len = 8; len >= 1; len >>= 1)
        #pragma unroll
        for (int l = 0; l < len; ++l)
            s[l] = faddr(s[l], s[l + len]);
    return s[0];
}

__device__ __forceinline__ void async_copy16(const void* g, void* l) {
    __builtin_amdgcn_global_load_lds(
        (const __attribute__((address_space(1))) void*)g,
        (__attribute__((address_space(3))) void*)l, 16, 0, 0);
}

// ---------------- prep: W -> swizzled bf16 hi/lo, exact s2, zero accumulators ----
__global__ void vq_prep(const float* __restrict__ W, unsigned short* __restrict__ Whi,
                        unsigned short* __restrict__ Wlo, float* __restrict__ s2g,
                        int* __restrict__ counts, int* __restrict__ ticket,
                        double* __restrict__ loss_acc) {
    int gid = blockIdx.x * NTH + threadIdx.x;   // 64 blocks -> 16384 threads
    for (int e = gid; e < K_CODES * DIM; e += 16384) {
        float x = W[e];
        unsigned short hi = f2bf(x);
        unsigned short lo = f2bf(__fsub_rn(x, bf2f(hi)));
        int j = e >> 6, k = e & 63;
        int pos = j * 64 + (((k >> 3) ^ (j & 7)) << 3) + (k & 7);
        Whi[pos] = hi; Wlo[pos] = lo;
    }
    if (gid < K_CODES) { s2g[gid] = sumsq64_np(W + gid * 64); counts[gid] = 0; }
    if (gid == 0) { *loss_acc = 0.0; *ticket = 0; }
}

// ---------------- final scalars (run by the last main block via ticket) ----------
__device__ void final_scalars(int* __restrict__ counts, double* __restrict__ loss_acc,
                              float* __restrict__ out, int tid, double* hred) {
    double h = 0.0;
    for (int j = tid; j < K_CODES; j += NTHM) {
        int cj = atomicAdd(&counts[j], 0);            // coherent read
        double p = (double)cj / 65536.0;
        h += p * log(p + 1e-10);
    }
    #pragma unroll
    for (int off = 32; off >= 1; off >>= 1) h += __shfl_down(h, off, 64);
    if ((tid & 63) == 0) hred[tid >> 6] = h;
    __syncthreads();
    if (tid == 0) {
        double H = 0.0;
        #pragma unroll
        for (int w = 0; w < 8; ++w) H += hred[w];
        out[OFF_PERP] = (float)exp(-H);
        double ls = atomicAdd(loss_acc, 0.0);         // coherent read
        float Lf = (float)(ls / 4194304.0);
        out[0] = faddr(Lf, fmulr(0.25f, Lf));
    }
}

// ---------------- main: MFMA top2 + candidate masks + in-block exact resolve -----
// Hot loop = round-1's proven 56us structure (8 waves: tg 0..3 token groups x
// chd 0..1 code halves, plain __syncthreads dbuf) + 3 VALU/elem candidate-mask
// tracking. LDS union U (32KB): X bf16 staging -> W dbuf -> masks/merge/flist.
// Fallback tokens resolved IN-BLOCK: one wave per token, each lane checks its
// mask (~1 candidate), bit-exact fmaf-chain dot from global (L2-hot), packed
// u64 argmin == validated full-rescan semantics. Ticket -> last block emits
// scalars. launch_bounds min-waves=4 (cap 128): R1 core 64 + ~10 mask regs,
// no spill expected (R5's spill was top-3 state at this cap).
__global__ __launch_bounds__(NTHM, 4)
void vq_main(const float* __restrict__ X, const float* __restrict__ W,
             const unsigned short* __restrict__ WhiG, const unsigned short* __restrict__ WloG,
             const float* __restrict__ s2g, float* __restrict__ out,
             double* __restrict__ loss_acc, int* __restrict__ counts,
             int* __restrict__ ticket) {
    __shared__ __align__(16) char U[32768];
    __shared__ __align__(16) float s2s[K_CODES];
    __shared__ int fcount, lastflag;
    __shared__ double lred[8];

    // phase A: X bf16 staging
    unsigned short* xs_hi = (unsigned short*)U;                 // [0,16K)
    unsigned short* xs_lo = (unsigned short*)(U + 16384);       // [16K,32K)
    // phase B: W dbuf — hi buf b at b*8192, lo at 16384 + b*8192
    // phase C (post-loop): masks + merge + flist
    unsigned* maskL = (unsigned*)U;                             // [8][64][8] u32, 16KB
    float (*sm1)[TPB] = (float (*)[TPB])(U + 16384);            // [2][128]
    float (*sm2)[TPB] = (float (*)[TPB])(U + 17408);
    int   (*si1)[TPB] = (int   (*)[TPB])(U + 18432);
    int*   fidx  = (int*)(U + 19456);                           // [128]
    int*   flist = (int*)(U + 19968);                           // [128]
    float* s1f   = (float*)(U + 20480);                         // [128]

    const int tid  = threadIdx.x;
    const int lane = tid & 63, wave = tid >> 6;
    const int quad = lane >> 4, lrow = lane & 15;
    const int tg   = wave & 3;        // token group: 32 tokens
    const int chd  = wave >> 2;       // code half: 32 of each 64-code chunk
    const int t0   = blockIdx.x * TPB;

    if (tid == 0) fcount = 0;

    // stage s2 (4KB)
    if (tid < 256) *(f32x4*)&s2s[tid * 4] = *(const f32x4*)&s2g[tid * 4];
    // stage X tile as swizzled bf16 hi/lo (1024 groups of 8 floats)
    #pragma unroll
    for (int i = 0; i < 2; ++i) {
        int g = tid + NTHM * i;
        int t = g >> 3, kb = g & 7;
        const float* src = X + (size_t)(t0 + t) * DIM + kb * 8;
        float v[8];
        *(f32x4*)v       = *(const f32x4*)src;
        *(f32x4*)(v + 4) = *(const f32x4*)(src + 4);
        unsigned short h[8], l[8];
        #pragma unroll
        for (int k = 0; k < 8; ++k) {
            h[k] = f2bf(v[k]);
            l[k] = f2bf(__fsub_rn(v[k], bf2f(h[k])));
        }
        int base = t * 64 + ((kb ^ (t & 7)) << 3);
        *(s16x8*)&xs_hi[base] = *(s16x8*)h;
        *(s16x8*)&xs_lo[base] = *(s16x8*)l;
    }
    __syncthreads();   // X/s2 staged

    // A fragments in registers for the whole kernel: wave owns 32 tokens
    s16x8 a_h0[2], a_h1[2], a_l0[2], a_l1[2];
    #pragma unroll
    for (int rt = 0; rt < 2; ++rt) {
        int tf = tg * 32 + rt * 16 + lrow;
        int sA = tf & 7;
        a_h0[rt] = *(const s16x8*)&xs_hi[tf * 64 + (((0 + quad) ^ sA) << 3)];
        a_h1[rt] = *(const s16x8*)&xs_hi[tf * 64 + (((4 + quad) ^ sA) << 3)];
        a_l0[rt] = *(const s16x8*)&xs_lo[tf * 64 + (((0 + quad) ^ sA) << 3)];
        a_l1[rt] = *(const s16x8*)&xs_lo[tf * 64 + (((4 + quad) ^ sA) << 3)];
    }
    __syncthreads();   // frags retired -> U becomes W dbuf

    // prologue: prefetch chunk 0 into buf0, drain once
    {
        const char* gh = (const char*)WhiG;
        const char* gl = (const char*)WloG;
        async_copy16(gh + tid * 16, U + wave * 1024);
        async_copy16(gl + tid * 16, U + 16384 + wave * 1024);
    }
    __syncthreads();   // chunk 0 landed

    // top-2 of acc (max semantics; d = -2*acc exactly) + candidate masks
    float m1v[8], m2v[8]; int m1i[8]; unsigned cmask[8];
    #pragma unroll
    for (int ri = 0; ri < 8; ++ri) {
        m1v[ri] = -3.4e38f; m2v[ri] = -3.4e38f; m1i[ri] = 0x7fffffff; cmask[ri] = 0u;
    }

    for (int ch = 0; ch < NCH; ++ch) {
        const int buf = ch & 1;
        if (ch < NCH - 1) {   // prefetch next chunk into other buffer
            const char* gh = (const char*)WhiG + (ch + 1) * 8192;
            const char* gl = (const char*)WloG + (ch + 1) * 8192;
            async_copy16(gh + tid * 16, U + (buf ^ 1) * 8192 + wave * 1024);
            async_copy16(gl + tid * 16, U + 16384 + (buf ^ 1) * 8192 + wave * 1024);
        }
        const unsigned short* wh = (const unsigned short*)(U + buf * 8192);
        const unsigned short* wl = (const unsigned short*)(U + 16384 + buf * 8192);
        #pragma unroll
        for (int ct2 = 0; ct2 < 2; ++ct2) {
            int lc = chd * 32 + ct2 * 16 + lrow;  // local code (lane's C-column)
            int sB = lrow & 7;
            const unsigned short* bh = &wh[lc * 64];
            const unsigned short* bl = &wl[lc * 64];
            s16x8 b_h0 = *(const s16x8*)&bh[((0 + quad) ^ sB) << 3];
            s16x8 b_h1 = *(const s16x8*)&bh[((4 + quad) ^ sB) << 3];
            s16x8 b_l0 = *(const s16x8*)&bl[((0 + quad) ^ sB) << 3];
            s16x8 b_l1 = *(const s16x8*)&bl[((4 + quad) ^ sB) << 3];
            int jcode = ch * 64 + lc;
            float s2v = s2s[jcode];
            float ainit = fmulr(-0.5f, s2v);
            #pragma unroll
            for (int rt = 0; rt < 2; ++rt) {
                f32x4 acc = {ainit, ainit, ainit, ainit};   // acc = x.w - 0.5*s2
                acc = __builtin_amdgcn_mfma_f32_16x16x32_bf16(a_h0[rt], b_h0, acc, 0, 0, 0);
                acc = __builtin_amdgcn_mfma_f32_16x16x32_bf16(a_h1[rt], b_h1, acc, 0, 0, 0);
                acc = __builtin_amdgcn_mfma_f32_16x16x32_bf16(a_h0[rt], b_l0, acc, 0, 0, 0);
                acc = __builtin_amdgcn_mfma_f32_16x16x32_bf16(a_h1[rt], b_l1, acc, 0, 0, 0);
                acc = __builtin_amdgcn_mfma_f32_16x16x32_bf16(a_l0[rt], b_h0, acc, 0, 0, 0);
                acc = __builtin_amdgcn_mfma_f32_16x16x32_bf16(a_l1[rt], b_h1, acc, 0, 0, 0);
                #pragma unroll
                for (int r = 0; r < 4; ++r) {
                    float a = acc[r];
                    int ri = rt * 4 + r;
                    float thr = m1v[ri];            // old max (superset threshold)
                    bool gt = a > thr;              // strict: earliest code on ties
                    float sec = gt ? thr : a;
                    m2v[ri] = fmaxf(m2v[ri], sec);
                    m1v[ri] = gt ? a : thr;
                    m1i[ri] = gt ? jcode : m1i[ri];
                    unsigned cnd = (faddr(a, HMARGIN) > thr) ? 1u : 0u;
                    cmask[ri] = cmask[ri] * 2u + cnd;   // bit (ch,ct2) at 31-(2ch+ct2)
                }
            }
        }
        __syncthreads();   // drains next-chunk prefetch; protects buf reuse
    }

    // dump candidate masks (dbuf dead after final barrier above)
    {
        unsigned* mrow = maskL + (wave * 64 + lane) * 8;
        #pragma unroll
        for (int ri = 0; ri < 8; ++ri) mrow[ri] = cmask[ri];
    }

    // butterfly top-2 merge across the 16 lrow lanes (codes disjoint per lane)
    #pragma unroll
    for (int m = 1; m <= 8; m <<= 1) {
        #pragma unroll
        for (int ri = 0; ri < 8; ++ri) {
            float o1v = __shfl_xor(m1v[ri], m, 64);
            int   o1i = __shfl_xor(m1i[ri], m, 64);
            float o2v = __shfl_xor(m2v[ri], m, 64);
            bool take = (o1v > m1v[ri]) || (o1v == m1v[ri] && o1i < m1i[ri]);
            float loser = take ? m1v[ri] : o1v;
            m2v[ri] = fmaxf(fmaxf(m2v[ri], o2v), loser);
            if (take) { m1v[ri] = o1v; m1i[ri] = o1i; }
        }
    }
    // per-half results -> LDS for cross-wave merge
    if (lrow == 0) {
        #pragma unroll
        for (int ri = 0; ri < 8; ++ri) {
            int rt = ri >> 2, r = ri & 3;
            int t = tg * 32 + rt * 16 + quad * 4 + r;
            sm1[chd][t] = m1v[ri];
            sm2[chd][t] = m2v[ri];
            si1[chd][t] = m1i[ri];
        }
    }
    __syncthreads();
    if (tid < TPB) {
        int t = tid;
        float a1 = sm1[0][t], b1 = sm1[1][t];
        int   ia = si1[0][t], ib = si1[1][t];
        float a2 = sm2[0][t], b2 = sm2[1][t];
        bool take = (b1 > a1) || (b1 == a1 && ib < ia);
        float w1 = take ? b1 : a1;
        int   wi = take ? ib : ia;
        float loser = take ? a1 : b1;
        float w2 = fmaxf(fmaxf(a2, b2), loser);
        bool fb = __fsub_rn(w1, w2) < HMARGIN;   // == (d2 - d1) < MARGIN
        fidx[t] = fb ? (wi | (int)0x80000000) : wi;
        if (fb) { int p = atomicAdd(&fcount, 1); flist[p] = t; }
    }
    __syncthreads();

    const int fc = fcount;
    // s1 for fallback tokens (validated chain, from global X)
    if (tid < fc) s1f[tid] = sumsq64_np(X + (size_t)(t0 + flist[tid]) * 64);

    // epilogue for certain tokens, float4-vectorized (lsum stays in regs)
    double lsum = 0.0;
    #pragma unroll
    for (int i = 0; i < 4; ++i) {
        int e4 = tid + NTHM * i;             // 0..2047 float4 groups
        int t = e4 >> 4, d4 = (e4 & 15) * 4;
        int iv = fidx[t];
        if (iv >= 0) {
            f32x4 q = *(const f32x4*)&W[iv * 64 + d4];
            f32x4 x = *(const f32x4*)&X[(size_t)(t0 + t) * 64 + d4];
            *(f32x4*)&out[(size_t)OFF_Q + (size_t)(t0 + t) * 64 + d4] = q;
            #pragma unroll
            for (int c = 0; c < 4; ++c) {
                float df = __fsub_rn(q[c], x[c]);
                lsum += (double)fmulr(df, df);
            }
        }
    }
    if (tid < TPB) {
        int iv = fidx[tid];
        if (iv >= 0) {
            atomicAdd(&counts[iv], 1);
            out[(size_t)OFF_IDX + t0 + tid] = (float)iv;
        }
    }
    __syncthreads();   // masks/s1f/flist stable for resolve

    // -------- resolve: one wave per fallback token, lanes scan their masks ------
    // Candidate codes (superset of all within HMARGIN of w1) get the bit-exact
    // fmaf-chain dot (identical values/order to the validated fallback kernel);
    // packed u64 (d_bits<<32|idx) argmin == lexicographic (d>0 since s1 dominates).
    for (int ti = wave; ti < fc; ti += 8) {
        int t = flist[ti];
        int tok = t0 + t;
        unsigned long long best = ~0ULL;
        if (lane < 32) {
            int chd_ = lane >> 4, lr_ = lane & 15;
            int tg_ = t >> 5, rt_ = (t >> 4) & 1, quad_ = (t >> 2) & 3, r_ = t & 3;
            unsigned msk = maskL[((chd_ * 4 + tg_) * 64 + quad_ * 16 + lr_) * 8
                                 + rt_ * 4 + r_];
            const float* xr = X + (size_t)tok * 64;
            float s1 = s1f[ti];
            while (msk) {
                int p = __builtin_ctz(msk);
                msk &= msk - 1u;
                int q = 31 - p;                       // iteration order index
                int j = (q >> 1) * 64 + chd_ * 32 + ((q & 1) << 4) + lr_;
                const float* wr = W + (size_t)j * 64;
                float acc = 0.0f;
                #pragma unroll
                for (int kb = 0; kb < 16; ++kb) {     // exact sequential-k chain
                    f32x4 xv = *(const f32x4*)(xr + kb * 4);
                    f32x4 wv = *(const f32x4*)(wr + kb * 4);
                    acc = __builtin_fmaf(xv[0], wv[0], acc);
                    acc = __builtin_fmaf(xv[1], wv[1], acc);
                    acc = __builtin_fmaf(xv[2], wv[2], acc);
                    acc = __builtin_fmaf(xv[3], wv[3], acc);
                }
                float d = faddr(faddr(s1, s2s[j]), fmulr(-2.0f, acc));
                unsigned long long pk =
                    ((unsigned long long)__float_as_uint(d) << 32) |
                    (unsigned long long)(unsigned)j;
                best = (pk < best) ? pk : best;
            }
        }
        #pragma unroll
        for (int m = 32; m >= 1; m >>= 1) {
            unsigned long long o =
                ((unsigned long long)(unsigned)__shfl_xor((int)(best >> 32), m, 64) << 32) |
                (unsigned long long)(unsigned)__shfl_xor((int)(best & 0xffffffffu), m, 64);
            best = (o < best) ? o : best;
        }
        if (lane == 0) {
            int idx = (int)(best & 0xffffffffu);
            fidx[t] = idx;
            out[(size_t)OFF_IDX + tok] = (float)idx;
            atomicAdd(&counts[idx], 1);
        }
    }
    __syncthreads();   // resolved fidx visible

    // fallback tokens' Q write + loss
    for (int g = tid; g < fc * 16; g += NTHM) {
        int ti = g >> 4, d4 = (g & 15) * 4;
        int t = flist[ti];
        int idx = fidx[t];
        f32x4 q = *(const f32x4*)&W[idx * 64 + d4];
        f32x4 x = *(const f32x4*)&X[(size_t)(t0 + t) * 64 + d4];
        *(f32x4*)&out[(size_t)OFF_Q + (size_t)(t0 + t) * 64 + d4] = q;
        #pragma unroll
        for (int c = 0; c < 4; ++c) {
            float df = __fsub_rn(q[c], x[c]);
            lsum += (double)fmulr(df, df);
        }
    }

    // -------- loss reduction + global ticket -> last block emits scalars --------
    #pragma unroll
    for (int off = 32; off >= 1; off >>= 1) lsum += __shfl_down(lsum, off, 64);
    if (lane == 0) lred[wave] = lsum;
    __syncthreads();
    if (tid == 0) {
        double s = 0.0;
        #pragma unroll
        for (int w = 0; w < 8; ++w) s += lred[w];
        atomicAdd(loss_acc, s);
    }
    __threadfence();
    __syncthreads();
    if (tid == 0) lastflag = (atomicAdd(ticket, 1) == NBLK - 1);
    __syncthreads();
    if (lastflag) {
        __threadfence();
        final_scalars(counts, loss_acc, out, tid, lred);
    }
}

extern "C" void kernel_launch(void* const* d_in, const int* in_sizes, int n_in,
                              void* d_out, int out_size, void* d_ws, size_t ws_size,
                              hipStream_t stream) {
    const float* X = (const float*)d_in[0];
    const float* W = (const float*)d_in[1];
    float* out = (float*)d_out;
    char* ws = (char*)d_ws;
    double* loss_acc = (double*)(ws + WS_LOSS);
    int* ticket = (int*)(ws + WS_TICKET);
    int* counts = (int*)(ws + WS_COUNTS);
    unsigned short* Whi = (unsigned short*)(ws + WS_WHI);
    unsigned short* Wlo = (unsigned short*)(ws + WS_WLO);
    float* s2g = (float*)(ws + WS_S2);

    vq_prep<<<64, NTH, 0, stream>>>(W, Whi, Wlo, s2g, counts, ticket, loss_acc);
    vq_main<<<NBLK, NTHM, 0, stream>>>(X, W, Whi, Wlo, s2g, out,
                                       loss_acc, counts, ticket);
}